// Round 16
// baseline (196.706 us; speedup 1.0000x reference)
//
#include <hip/hip_runtime.h>
#include <hip/hip_bf16.h>

#define N_NODES 50000
#define N_EDGES 600000
#define HID 128
#define LN_EPS 1e-5f

#define SCAN_BLOCK 1024
#define SCAN_NBLK ((N_NODES + SCAN_BLOCK - 1) / SCAN_BLOCK)   // 49

typedef __attribute__((ext_vector_type(8))) short bf16x8;
typedef __attribute__((ext_vector_type(4))) float f32x4;

// f32 -> bf16 round-to-nearest-even
static __device__ __forceinline__ unsigned short f2bf(float f) {
    union { float f; unsigned u; } v; v.f = f;
    unsigned u = v.u;
    u += 0x7fffu + ((u >> 16) & 1u);
    return (unsigned short)(u >> 16);
}
static __device__ __forceinline__ float bflo(unsigned u) {
    union { unsigned u; float f; } c; c.u = u << 16; return c.f;
}
static __device__ __forceinline__ float bfhi(unsigned u) {
    union { unsigned u; float f; } c; c.u = u & 0xffff0000u; return c.f;
}

// ---------------------------------------------------------------- CSR build
__global__ __launch_bounds__(256) void count_kernel(const int* __restrict__ ei,
                                                    int* __restrict__ deg, int E) {
    int i = blockIdx.x * blockDim.x + threadIdx.x;
    if (i < E) atomicAdd(&deg[ei[E + i]], 1);
}

__global__ __launch_bounds__(SCAN_BLOCK) void deg_partial_kernel(const int* __restrict__ deg,
                                                                 int* __restrict__ partials, int n) {
    int t = threadIdx.x;
    int i = blockIdx.x * SCAN_BLOCK + t;
    int v = (i < n) ? deg[i] : 0;
    int s = v;
#pragma unroll
    for (int off = 1; off < 64; off <<= 1) s += __shfl_xor(s, off);
    __shared__ int ws[SCAN_BLOCK / 64];
    if ((t & 63) == 0) ws[t >> 6] = s;
    __syncthreads();
    if (t == 0) {
        int tot = 0;
#pragma unroll
        for (int w = 0; w < SCAN_BLOCK / 64; ++w) tot += ws[w];
        partials[blockIdx.x] = tot;
    }
}

__global__ __launch_bounds__(64) void scan_partials_kernel(int* __restrict__ partials,
                                                           int* __restrict__ row_ptr, int nblk) {
    int lane = threadIdx.x;
    int v = (lane < nblk) ? partials[lane] : 0;
    int incl = v;
#pragma unroll
    for (int off = 1; off < 64; off <<= 1) {
        int x = __shfl_up(incl, off);
        if (lane >= off) incl += x;
    }
    if (lane < nblk) partials[lane] = incl - v;
    if (lane == 63) row_ptr[N_NODES] = incl;
}

__global__ __launch_bounds__(SCAN_BLOCK) void scan_final_kernel(const int* __restrict__ deg,
                                                                const int* __restrict__ partials,
                                                                int* __restrict__ row_ptr,
                                                                int* __restrict__ cursor,
                                                                float* __restrict__ inv_cnt, int n) {
    int t = threadIdx.x;
    int i = blockIdx.x * SCAN_BLOCK + t;
    int v = (i < n) ? deg[i] : 0;
    int lane = t & 63, wid = t >> 6;
    int incl = v;
#pragma unroll
    for (int off = 1; off < 64; off <<= 1) {
        int x = __shfl_up(incl, off);
        if (lane >= off) incl += x;
    }
    __shared__ int ws[SCAN_BLOCK / 64];
    if (lane == 63) ws[wid] = incl;
    __syncthreads();
    int woff = 0;
    for (int w = 0; w < wid; ++w) woff += ws[w];
    int excl = partials[blockIdx.x] + woff + (incl - v);
    if (i < n) {
        row_ptr[i] = excl;
        cursor[i]  = excl;
        inv_cnt[i] = 1.0f / (float)(v + 1);
    }
}

__global__ __launch_bounds__(256) void fill_kernel(const int* __restrict__ ei,
                                                   int* __restrict__ cursor,
                                                   int* __restrict__ col, int E) {
    int i = blockIdx.x * blockDim.x + threadIdx.x;
    if (i < E) {
        int s = ei[i];
        int d = ei[E + i];
        int p = atomicAdd(&cursor[d], 1);
        col[p] = s;
    }
}

// ---------------------------------------------------------------- weight prep
__global__ __launch_bounds__(256) void wswz_all_kernel(const float* __restrict__ W1,
                                                       const float* __restrict__ W2,
                                                       const float* __restrict__ W3,
                                                       unsigned short* __restrict__ d1,
                                                       unsigned short* __restrict__ d2,
                                                       unsigned short* __restrict__ d3) {
    int i = blockIdx.x * 256 + threadIdx.x;
    const float* W; unsigned short* dst; int idx;
    if (i < 64 * 128)              { W = W1; dst = d1; idx = i; }
    else if (i < (64 + 128) * 128) { W = W2; dst = d2; idx = i - 64 * 128; }
    else if (i < (64 + 256) * 128) { W = W3; dst = d3; idx = i - (64 + 128) * 128; }
    else return;
    int k = idx >> 7, col = idx & 127;
    dst[(((k >> 3) * 128) + col) * 8 + (k & 7)] = f2bf(W[idx]);
}

// ---------------------------------------------------------------- MFMA GEMM
template <int K, int AF32>
__global__ __launch_bounds__(256) void gemm_mfma_kernel(
    const void* __restrict__ Ap,
    const unsigned short* __restrict__ Wswz,
    const float* __restrict__ bias,
    unsigned short* __restrict__ out, int N) {
    __shared__ unsigned short Bl[K * 128];
    __shared__ float bl[128];
    int t = threadIdx.x;
    for (int i = t; i < K * 16; i += 256)
        ((int4*)Bl)[i] = ((const int4*)Wswz)[i];
    if (t < 128) bl[t] = bias[t];
    __syncthreads();

    int lane = t & 63;
    int w = t >> 6;
    int r0 = blockIdx.x * 64 + w * 16;
    int colb = lane & 15;
    int kg = lane >> 4;
    int rowa = min(r0 + colb, N - 1);

    f32x4 acc[8];
#pragma unroll
    for (int c = 0; c < 8; ++c) acc[c] = (f32x4){0.f, 0.f, 0.f, 0.f};

    const bf16x8* Blv = (const bf16x8*)Bl;
    for (int s = 0; s < K; s += 32) {
        bf16x8 afrag;
        if (AF32) {
            const float* Af = (const float*)Ap;
            float4 a0 = *(const float4*)&Af[(size_t)rowa * K + s + kg * 8];
            float4 a1 = *(const float4*)&Af[(size_t)rowa * K + s + kg * 8 + 4];
            afrag[0] = (short)f2bf(a0.x); afrag[1] = (short)f2bf(a0.y);
            afrag[2] = (short)f2bf(a0.z); afrag[3] = (short)f2bf(a0.w);
            afrag[4] = (short)f2bf(a1.x); afrag[5] = (short)f2bf(a1.y);
            afrag[6] = (short)f2bf(a1.z); afrag[7] = (short)f2bf(a1.w);
        } else {
            const unsigned short* Ab = (const unsigned short*)Ap;
            afrag = *(const bf16x8*)&Ab[(size_t)rowa * K + s + kg * 8];
        }
        int kb = (s >> 3) + kg;
#pragma unroll
        for (int c = 0; c < 8; ++c) {
            bf16x8 bfrag = Blv[kb * 128 + c * 16 + colb];
            acc[c] = __builtin_amdgcn_mfma_f32_16x16x32_bf16(afrag, bfrag, acc[c], 0, 0, 0);
        }
    }
#pragma unroll
    for (int c = 0; c < 8; ++c) {
        int col = c * 16 + colb;
        float bv = bl[col];
#pragma unroll
        for (int r = 0; r < 4; ++r) {
            int ro = r0 + kg * 4 + r;
            if (ro < N) out[(size_t)ro * 128 + col] = f2bf(acc[c][r] + bv);
        }
    }
}

// ------------------------------------------------- aggregate + mean + ReLU + LN
// 4 nodes per wave, 16 lanes per node, dwordx4/lane. 8-edge batches.
template <int BF16OUT>
__global__ __launch_bounds__(256) void agg_norm_kernel(
    const unsigned short* __restrict__ hb,
    const int* __restrict__ row_ptr,
    const int* __restrict__ col,
    const float* __restrict__ inv_cnt,
    const float* __restrict__ g, const float* __restrict__ be,
    void* __restrict__ outp, int N) {
    int tid  = blockIdx.x * 256 + threadIdx.x;
    int wave = tid >> 6;
    int lane = threadIdx.x & 63;
    int sub  = lane >> 4;
    int lc   = lane & 15;
    int n    = wave * 4 + sub;
    bool act = n < N;
    int nc   = act ? n : N - 1;

    const uint4* h4 = (const uint4*)hb;

    float a[8];
    {
        uint4 u = h4[(size_t)nc * 16 + lc];
        a[0] = bflo(u.x); a[1] = bfhi(u.x);
        a[2] = bflo(u.y); a[3] = bfhi(u.y);
        a[4] = bflo(u.z); a[5] = bfhi(u.z);
        a[6] = bflo(u.w); a[7] = bfhi(u.w);
    }

    int beg = row_ptr[nc], end = row_ptr[nc + 1];
    int cnt = end - beg;
    int lim = min(cnt, 32);
    int c0 = (lc < cnt)      ? col[beg + lc]      : nc;
    int c1 = (16 + lc < cnt) ? col[beg + 16 + lc] : nc;

    int wlim = lim;
    wlim = max(wlim, __shfl_xor(wlim, 16));
    wlim = max(wlim, __shfl_xor(wlim, 32));
    int nGrp = (wlim + 7) >> 3;

    for (int gi = 0; gi < nGrp; ++gi) {
        int e0 = gi * 8;
        int jj[8]; float mm[8];
#pragma unroll
        for (int q = 0; q < 8; ++q) {
            int iq = max(min(e0 + q, lim - 1), 0);
            mm[q] = (e0 + q < lim) ? 1.0f : 0.0f;
            int sl = sub * 16 + (iq & 15);
            int jA = __shfl(c0, sl);
            int jB = __shfl(c1, sl);
            jj[q] = (iq < 16) ? jA : jB;
        }
        uint4 u[8];
#pragma unroll
        for (int q = 0; q < 8; ++q) u[q] = h4[(size_t)jj[q] * 16 + lc];
#pragma unroll
        for (int q = 0; q < 8; ++q) {
            a[0] = fmaf(mm[q], bflo(u[q].x), a[0]); a[1] = fmaf(mm[q], bfhi(u[q].x), a[1]);
            a[2] = fmaf(mm[q], bflo(u[q].y), a[2]); a[3] = fmaf(mm[q], bfhi(u[q].y), a[3]);
            a[4] = fmaf(mm[q], bflo(u[q].z), a[4]); a[5] = fmaf(mm[q], bfhi(u[q].z), a[5]);
            a[6] = fmaf(mm[q], bflo(u[q].w), a[6]); a[7] = fmaf(mm[q], bfhi(u[q].w), a[7]);
        }
    }
    for (int e = 32; e < cnt; ++e) {
        int j = col[beg + e];
        uint4 u = h4[(size_t)j * 16 + lc];
        a[0] += bflo(u.x); a[1] += bfhi(u.x);
        a[2] += bflo(u.y); a[3] += bfhi(u.y);
        a[4] += bflo(u.z); a[5] += bfhi(u.z);
        a[6] += bflo(u.w); a[7] += bfhi(u.w);
    }

    float ic = inv_cnt[nc];
    float s[8], sum = 0.f, sq = 0.f;
#pragma unroll
    for (int k = 0; k < 8; ++k) {
        s[k] = fmaxf(a[k] * ic, 0.0f);
        sum += s[k];
        sq  += s[k] * s[k];
    }
#pragma unroll
    for (int off = 1; off < 16; off <<= 1) {
        sum += __shfl_xor(sum, off);
        sq  += __shfl_xor(sq, off);
    }
    float mu  = sum * (1.0f / 128.0f);
    float var = sq * (1.0f / 128.0f) - mu * mu;
    float rs  = rsqrtf(var + LN_EPS);

    const float4* gv  = (const float4*)g;
    const float4* bv  = (const float4*)be;
    float4 gA = gv[lc * 2], gB = gv[lc * 2 + 1];
    float4 bA = bv[lc * 2], bB = bv[lc * 2 + 1];
    float o[8];
    o[0] = gA.x * (s[0] - mu) * rs + bA.x;
    o[1] = gA.y * (s[1] - mu) * rs + bA.y;
    o[2] = gA.z * (s[2] - mu) * rs + bA.z;
    o[3] = gA.w * (s[3] - mu) * rs + bA.w;
    o[4] = gB.x * (s[4] - mu) * rs + bB.x;
    o[5] = gB.y * (s[5] - mu) * rs + bB.y;
    o[6] = gB.z * (s[6] - mu) * rs + bB.z;
    o[7] = gB.w * (s[7] - mu) * rs + bB.w;

    if (!act) return;
    if (BF16OUT) {
        uint4 p;
        p.x = (unsigned)f2bf(o[0]) | ((unsigned)f2bf(o[1]) << 16);
        p.y = (unsigned)f2bf(o[2]) | ((unsigned)f2bf(o[3]) << 16);
        p.z = (unsigned)f2bf(o[4]) | ((unsigned)f2bf(o[5]) << 16);
        p.w = (unsigned)f2bf(o[6]) | ((unsigned)f2bf(o[7]) << 16);
        ((uint4*)outp)[(size_t)nc * 16 + lc] = p;
    } else {
        float4 f0; f0.x = o[0]; f0.y = o[1]; f0.z = o[2]; f0.w = o[3];
        float4 f1; f1.x = o[4]; f1.y = o[5]; f1.z = o[6]; f1.w = o[7];
        ((float4*)outp)[(size_t)nc * 32 + lc * 2]     = f0;
        ((float4*)outp)[(size_t)nc * 32 + lc * 2 + 1] = f1;
    }
}

// ---------------------------------------------------------------- launch
extern "C" void kernel_launch(void* const* d_in, const int* in_sizes, int n_in,
                              void* d_out, int out_size, void* d_ws, size_t ws_size,
                              hipStream_t stream) {
    const float* x  = (const float*)d_in[0];
    const int*   ei = (const int*)d_in[1];
    const float* W1 = (const float*)d_in[2];
    const float* b1 = (const float*)d_in[3];
    const float* W2 = (const float*)d_in[4];
    const float* b2 = (const float*)d_in[5];
    const float* W3 = (const float*)d_in[6];
    const float* b3 = (const float*)d_in[7];
    const float* g1 = (const float*)d_in[8];
    const float* be1 = (const float*)d_in[9];
    const float* g2 = (const float*)d_in[10];
    const float* be2 = (const float*)d_in[11];
    const float* g3 = (const float*)d_in[12];
    const float* be3 = (const float*)d_in[13];
    float* out = (float*)d_out;

    const int N = N_NODES, E = N_EDGES;
    char* w = (char*)d_ws;
    unsigned short* hb   = (unsigned short*)w; w += (size_t)N * 128 * 2;
    unsigned short* midb = (unsigned short*)w; w += (size_t)N * 128 * 2;
    unsigned short* w1s  = (unsigned short*)w; w += (size_t)64 * 128 * 2;
    unsigned short* w2s  = (unsigned short*)w; w += (size_t)128 * 128 * 2;
    unsigned short* w3s  = (unsigned short*)w; w += (size_t)128 * 128 * 2;
    int*   col    = (int*)w;    w += (size_t)E * sizeof(int);
    int*   rowp   = (int*)w;    w += (size_t)(N + 1) * sizeof(int);
    int*   cursor = (int*)w;    w += (size_t)N * sizeof(int);
    int*   deg    = (int*)w;    w += (size_t)N * sizeof(int);
    float* invc   = (float*)w;  w += (size_t)N * sizeof(float);
    int*   parts  = (int*)w;    w += (size_t)SCAN_NBLK * sizeof(int);

    // CSR build
    hipMemsetAsync(deg, 0, (size_t)N * sizeof(int), stream);
    count_kernel<<<(E + 255) / 256, 256, 0, stream>>>(ei, deg, E);
    deg_partial_kernel<<<SCAN_NBLK, SCAN_BLOCK, 0, stream>>>(deg, parts, N);
    scan_partials_kernel<<<1, 64, 0, stream>>>(parts, rowp, SCAN_NBLK);
    scan_final_kernel<<<SCAN_NBLK, SCAN_BLOCK, 0, stream>>>(deg, parts, rowp, cursor, invc, N);
    fill_kernel<<<(E + 255) / 256, 256, 0, stream>>>(ei, cursor, col, E);

    // weight prep (one launch for all three)
    wswz_all_kernel<<<((64 + 256) * 128 + 255) / 256, 256, 0, stream>>>(W1, W2, W3, w1s, w2s, w3s);

    const int gemm_blocks = (N + 63) / 64;
    const int agg_blocks  = (N + 15) / 16;

    // layer 1 (GEMM reads f32 x directly)
    gemm_mfma_kernel<64, 1><<<gemm_blocks, 256, 0, stream>>>(x, w1s, b1, hb, N);
    agg_norm_kernel<1><<<agg_blocks, 256, 0, stream>>>(hb, rowp, col, invc, g1, be1, midb, N);
    // layer 2
    gemm_mfma_kernel<128, 0><<<gemm_blocks, 256, 0, stream>>>(midb, w2s, b2, hb, N);
    agg_norm_kernel<1><<<agg_blocks, 256, 0, stream>>>(hb, rowp, col, invc, g2, be2, midb, N);
    // layer 3
    gemm_mfma_kernel<128, 0><<<gemm_blocks, 256, 0, stream>>>(midb, w3s, b3, hb, N);
    agg_norm_kernel<0><<<agg_blocks, 256, 0, stream>>>(hb, rowp, col, invc, g3, be3, out, N);
}

// Round 17
// 185.421 us; speedup vs baseline: 1.0609x; 1.0609x over previous
//
#include <hip/hip_runtime.h>
#include <hip/hip_bf16.h>

#define N_NODES 50000
#define N_EDGES 600000
#define HID 128
#define LN_EPS 1e-5f

#define SCAN_BLOCK 1024
#define SCAN_NBLK ((N_NODES + SCAN_BLOCK - 1) / SCAN_BLOCK)   // 49

#define GB1 ((N_NODES + 63) / 64)        // 782 gemm1 blocks
#define CB  ((N_EDGES + 255) / 256)      // 2344 count blocks
#define WB  (((64 + 256) * 128) / 256)   // 160 wswz blocks

typedef __attribute__((ext_vector_type(8))) short bf16x8;
typedef __attribute__((ext_vector_type(4))) float f32x4;

// f32 -> bf16 round-to-nearest-even
static __device__ __forceinline__ unsigned short f2bf(float f) {
    union { float f; unsigned u; } v; v.f = f;
    unsigned u = v.u;
    u += 0x7fffu + ((u >> 16) & 1u);
    return (unsigned short)(u >> 16);
}
static __device__ __forceinline__ float bflo(unsigned u) {
    union { unsigned u; float f; } c; c.u = u << 16; return c.f;
}
static __device__ __forceinline__ float bfhi(unsigned u) {
    union { unsigned u; float f; } c; c.u = u & 0xffff0000u; return c.f;
}

// ---------------------------------------------------------------- K1: gemm1 | count | wswz
// All three phases depend only on kernel-entry inputs -> safe blockIdx branch.
__global__ __launch_bounds__(256) void mega1_kernel(
    const float* __restrict__ x,              // [N,64] f32
    const unsigned short* __restrict__ W1swz, // gemm1 weights (already swizzled? no - see below)
    const float* __restrict__ b1,
    unsigned short* __restrict__ hb,          // gemm1 out
    const int* __restrict__ ei,               // edges
    int* __restrict__ deg,                    // count out
    const float* __restrict__ W1,             // wswz inputs
    const float* __restrict__ W2,
    const float* __restrict__ W3,
    unsigned short* __restrict__ d1,
    unsigned short* __restrict__ d2,
    unsigned short* __restrict__ d3, int N, int E) {
    __shared__ unsigned short Bl[64 * 128];
    __shared__ float bl[128];
    int bid = blockIdx.x;
    int t = threadIdx.x;

    if (bid < GB1) {
        // ---- gemm1: hb = bf16(x @ W1 + b1), W1 swizzled IN-KERNEL from f32
        // (wswz output not yet available; swizzle W1 directly here: 64x128 = 8K elems)
        for (int i = t; i < 64 * 128; i += 256) {
            int k = i >> 7, col = i & 127;
            Bl[(((k >> 3) * 128) + col) * 8 + (k & 7)] = f2bf(W1[i]);
        }
        if (t < 128) bl[t] = b1[t];
        __syncthreads();

        int lane = t & 63;
        int w = t >> 6;
        int r0 = bid * 64 + w * 16;
        int colb = lane & 15;
        int kg = lane >> 4;
        int rowa = min(r0 + colb, N - 1);

        f32x4 acc[8];
#pragma unroll
        for (int c = 0; c < 8; ++c) acc[c] = (f32x4){0.f, 0.f, 0.f, 0.f};

        const bf16x8* Blv = (const bf16x8*)Bl;
        for (int s = 0; s < 64; s += 32) {
            bf16x8 afrag;
            float4 a0 = *(const float4*)&x[(size_t)rowa * 64 + s + kg * 8];
            float4 a1 = *(const float4*)&x[(size_t)rowa * 64 + s + kg * 8 + 4];
            afrag[0] = (short)f2bf(a0.x); afrag[1] = (short)f2bf(a0.y);
            afrag[2] = (short)f2bf(a0.z); afrag[3] = (short)f2bf(a0.w);
            afrag[4] = (short)f2bf(a1.x); afrag[5] = (short)f2bf(a1.y);
            afrag[6] = (short)f2bf(a1.z); afrag[7] = (short)f2bf(a1.w);
            int kb = (s >> 3) + kg;
#pragma unroll
            for (int c = 0; c < 8; ++c) {
                bf16x8 bfrag = Blv[kb * 128 + c * 16 + colb];
                acc[c] = __builtin_amdgcn_mfma_f32_16x16x32_bf16(afrag, bfrag, acc[c], 0, 0, 0);
            }
        }
#pragma unroll
        for (int c = 0; c < 8; ++c) {
            int col = c * 16 + colb;
            float bv = bl[col];
#pragma unroll
            for (int r = 0; r < 4; ++r) {
                int ro = r0 + kg * 4 + r;
                if (ro < N) hb[(size_t)ro * 128 + col] = f2bf(acc[c][r] + bv);
            }
        }
    } else if (bid < GB1 + CB) {
        // ---- count
        int i = (bid - GB1) * 256 + t;
        if (i < E) atomicAdd(&deg[ei[E + i]], 1);
    } else {
        // ---- wswz for W2/W3 (W1 handled in-kernel by gemm1 blocks) + W1 too
        // (W1 swizzle output d1 is unused now but kept for symmetry/cheap)
        int i = (bid - GB1 - CB) * 256 + t;
        const float* W; unsigned short* dst; int idx;
        if (i < 64 * 128)              { W = W1; dst = d1; idx = i; }
        else if (i < (64 + 128) * 128) { W = W2; dst = d2; idx = i - 64 * 128; }
        else if (i < (64 + 256) * 128) { W = W3; dst = d3; idx = i - (64 + 128) * 128; }
        else return;
        int k = idx >> 7, col = idx & 127;
        dst[(((k >> 3) * 128) + col) * 8 + (k & 7)] = f2bf(W[idx]);
    }
}

// ---------------------------------------------------------------- CSR scan
__global__ __launch_bounds__(SCAN_BLOCK) void deg_partial_kernel(const int* __restrict__ deg,
                                                                 int* __restrict__ partials, int n) {
    int t = threadIdx.x;
    int i = blockIdx.x * SCAN_BLOCK + t;
    int v = (i < n) ? deg[i] : 0;
    int s = v;
#pragma unroll
    for (int off = 1; off < 64; off <<= 1) s += __shfl_xor(s, off);
    __shared__ int ws[SCAN_BLOCK / 64];
    if ((t & 63) == 0) ws[t >> 6] = s;
    __syncthreads();
    if (t == 0) {
        int tot = 0;
#pragma unroll
        for (int w = 0; w < SCAN_BLOCK / 64; ++w) tot += ws[w];
        partials[blockIdx.x] = tot;
    }
}

// block-exclusive scan; each block serially prefixes the 49 partials itself.
__global__ __launch_bounds__(SCAN_BLOCK) void scan_final_kernel(const int* __restrict__ deg,
                                                                const int* __restrict__ partials,
                                                                int* __restrict__ row_ptr,
                                                                int* __restrict__ cursor,
                                                                float* __restrict__ inv_cnt, int n) {
    __shared__ int base_sh;
    __shared__ int ws[SCAN_BLOCK / 64];
    int t = threadIdx.x;
    if (t == 0) {
        int pre = 0, tot = 0;
        for (int i = 0; i < SCAN_NBLK; ++i) {
            int p = partials[i];
            if (i < (int)blockIdx.x) pre += p;
            tot += p;
        }
        base_sh = pre;
        if (blockIdx.x == 0) row_ptr[n] = tot;
    }
    int i = blockIdx.x * SCAN_BLOCK + t;
    int v = (i < n) ? deg[i] : 0;
    int lane = t & 63, wid = t >> 6;
    int incl = v;
#pragma unroll
    for (int off = 1; off < 64; off <<= 1) {
        int x = __shfl_up(incl, off);
        if (lane >= off) incl += x;
    }
    if (lane == 63) ws[wid] = incl;
    __syncthreads();
    int woff = 0;
    for (int w = 0; w < wid; ++w) woff += ws[w];
    int excl = base_sh + woff + (incl - v);
    if (i < n) {
        row_ptr[i] = excl;
        cursor[i]  = excl;
        inv_cnt[i] = 1.0f / (float)(v + 1);
    }
}

__global__ __launch_bounds__(256) void fill_kernel(const int* __restrict__ ei,
                                                   int* __restrict__ cursor,
                                                   int* __restrict__ col, int E) {
    int i = blockIdx.x * blockDim.x + threadIdx.x;
    if (i < E) {
        int s = ei[i];
        int d = ei[E + i];
        int p = atomicAdd(&cursor[d], 1);
        col[p] = s;
    }
}

// ---------------------------------------------------------------- MFMA GEMM (layers 2,3)
template <int K>
__global__ __launch_bounds__(256) void gemm_mfma_kernel(
    const unsigned short* __restrict__ Ab,
    const unsigned short* __restrict__ Wswz,
    const float* __restrict__ bias,
    unsigned short* __restrict__ out, int N) {
    __shared__ unsigned short Bl[K * 128];
    __shared__ float bl[128];
    int t = threadIdx.x;
    for (int i = t; i < K * 16; i += 256)
        ((int4*)Bl)[i] = ((const int4*)Wswz)[i];
    if (t < 128) bl[t] = bias[t];
    __syncthreads();

    int lane = t & 63;
    int w = t >> 6;
    int r0 = blockIdx.x * 64 + w * 16;
    int colb = lane & 15;
    int kg = lane >> 4;
    int rowa = min(r0 + colb, N - 1);

    f32x4 acc[8];
#pragma unroll
    for (int c = 0; c < 8; ++c) acc[c] = (f32x4){0.f, 0.f, 0.f, 0.f};

    const bf16x8* Blv = (const bf16x8*)Bl;
    for (int s = 0; s < K; s += 32) {
        bf16x8 afrag = *(const bf16x8*)&Ab[(size_t)rowa * K + s + kg * 8];
        int kb = (s >> 3) + kg;
#pragma unroll
        for (int c = 0; c < 8; ++c) {
            bf16x8 bfrag = Blv[kb * 128 + c * 16 + colb];
            acc[c] = __builtin_amdgcn_mfma_f32_16x16x32_bf16(afrag, bfrag, acc[c], 0, 0, 0);
        }
    }
#pragma unroll
    for (int c = 0; c < 8; ++c) {
        int col = c * 16 + colb;
        float bv = bl[col];
#pragma unroll
        for (int r = 0; r < 4; ++r) {
            int ro = r0 + kg * 4 + r;
            if (ro < N) out[(size_t)ro * 128 + col] = f2bf(acc[c][r] + bv);
        }
    }
}

// ------------------------------------------------- aggregate + mean + ReLU + LN
template <int BF16OUT>
__global__ __launch_bounds__(256) void agg_norm_kernel(
    const unsigned short* __restrict__ hb,
    const int* __restrict__ row_ptr,
    const int* __restrict__ col,
    const float* __restrict__ inv_cnt,
    const float* __restrict__ g, const float* __restrict__ be,
    void* __restrict__ outp, int N) {
    int tid  = blockIdx.x * 256 + threadIdx.x;
    int wave = tid >> 6;
    int lane = threadIdx.x & 63;
    int sub  = lane >> 4;
    int lc   = lane & 15;
    int n    = wave * 4 + sub;
    bool act = n < N;
    int nc   = act ? n : N - 1;

    const uint4* h4 = (const uint4*)hb;

    float a[8];
    {
        uint4 u = h4[(size_t)nc * 16 + lc];
        a[0] = bflo(u.x); a[1] = bfhi(u.x);
        a[2] = bflo(u.y); a[3] = bfhi(u.y);
        a[4] = bflo(u.z); a[5] = bfhi(u.z);
        a[6] = bflo(u.w); a[7] = bfhi(u.w);
    }

    int beg = row_ptr[nc], end = row_ptr[nc + 1];
    int cnt = end - beg;
    int lim = min(cnt, 32);
    int c0 = (lc < cnt)      ? col[beg + lc]      : nc;
    int c1 = (16 + lc < cnt) ? col[beg + 16 + lc] : nc;

    int wlim = lim;
    wlim = max(wlim, __shfl_xor(wlim, 16));
    wlim = max(wlim, __shfl_xor(wlim, 32));
    int nGrp = (wlim + 7) >> 3;

    for (int gi = 0; gi < nGrp; ++gi) {
        int e0 = gi * 8;
        int jj[8]; float mm[8];
#pragma unroll
        for (int q = 0; q < 8; ++q) {
            int iq = max(min(e0 + q, lim - 1), 0);
            mm[q] = (e0 + q < lim) ? 1.0f : 0.0f;
            int sl = sub * 16 + (iq & 15);
            int jA = __shfl(c0, sl);
            int jB = __shfl(c1, sl);
            jj[q] = (iq < 16) ? jA : jB;
        }
        uint4 u[8];
#pragma unroll
        for (int q = 0; q < 8; ++q) u[q] = h4[(size_t)jj[q] * 16 + lc];
#pragma unroll
        for (int q = 0; q < 8; ++q) {
            a[0] = fmaf(mm[q], bflo(u[q].x), a[0]); a[1] = fmaf(mm[q], bfhi(u[q].x), a[1]);
            a[2] = fmaf(mm[q], bflo(u[q].y), a[2]); a[3] = fmaf(mm[q], bfhi(u[q].y), a[3]);
            a[4] = fmaf(mm[q], bflo(u[q].z), a[4]); a[5] = fmaf(mm[q], bfhi(u[q].z), a[5]);
            a[6] = fmaf(mm[q], bflo(u[q].w), a[6]); a[7] = fmaf(mm[q], bfhi(u[q].w), a[7]);
        }
    }
    for (int e = 32; e < cnt; ++e) {
        int j = col[beg + e];
        uint4 u = h4[(size_t)j * 16 + lc];
        a[0] += bflo(u.x); a[1] += bfhi(u.x);
        a[2] += bflo(u.y); a[3] += bfhi(u.y);
        a[4] += bflo(u.z); a[5] += bfhi(u.z);
        a[6] += bflo(u.w); a[7] += bfhi(u.w);
    }

    float ic = inv_cnt[nc];
    float s[8], sum = 0.f, sq = 0.f;
#pragma unroll
    for (int k = 0; k < 8; ++k) {
        s[k] = fmaxf(a[k] * ic, 0.0f);
        sum += s[k];
        sq  += s[k] * s[k];
    }
#pragma unroll
    for (int off = 1; off < 16; off <<= 1) {
        sum += __shfl_xor(sum, off);
        sq  += __shfl_xor(sq, off);
    }
    float mu  = sum * (1.0f / 128.0f);
    float var = sq * (1.0f / 128.0f) - mu * mu;
    float rs  = rsqrtf(var + LN_EPS);

    const float4* gv  = (const float4*)g;
    const float4* bv  = (const float4*)be;
    float4 gA = gv[lc * 2], gB = gv[lc * 2 + 1];
    float4 bA = bv[lc * 2], bB = bv[lc * 2 + 1];
    float o[8];
    o[0] = gA.x * (s[0] - mu) * rs + bA.x;
    o[1] = gA.y * (s[1] - mu) * rs + bA.y;
    o[2] = gA.z * (s[2] - mu) * rs + bA.z;
    o[3] = gA.w * (s[3] - mu) * rs + bA.w;
    o[4] = gB.x * (s[4] - mu) * rs + bB.x;
    o[5] = gB.y * (s[5] - mu) * rs + bB.y;
    o[6] = gB.z * (s[6] - mu) * rs + bB.z;
    o[7] = gB.w * (s[7] - mu) * rs + bB.w;

    if (!act) return;
    if (BF16OUT) {
        uint4 p;
        p.x = (unsigned)f2bf(o[0]) | ((unsigned)f2bf(o[1]) << 16);
        p.y = (unsigned)f2bf(o[2]) | ((unsigned)f2bf(o[3]) << 16);
        p.z = (unsigned)f2bf(o[4]) | ((unsigned)f2bf(o[5]) << 16);
        p.w = (unsigned)f2bf(o[6]) | ((unsigned)f2bf(o[7]) << 16);
        ((uint4*)outp)[(size_t)nc * 16 + lc] = p;
    } else {
        float4 f0; f0.x = o[0]; f0.y = o[1]; f0.z = o[2]; f0.w = o[3];
        float4 f1; f1.x = o[4]; f1.y = o[5]; f1.z = o[6]; f1.w = o[7];
        ((float4*)outp)[(size_t)nc * 32 + lc * 2]     = f0;
        ((float4*)outp)[(size_t)nc * 32 + lc * 2 + 1] = f1;
    }
}

// ---------------------------------------------------------------- launch
extern "C" void kernel_launch(void* const* d_in, const int* in_sizes, int n_in,
                              void* d_out, int out_size, void* d_ws, size_t ws_size,
                              hipStream_t stream) {
    const float* x  = (const float*)d_in[0];
    const int*   ei = (const int*)d_in[1];
    const float* W1 = (const float*)d_in[2];
    const float* b1 = (const float*)d_in[3];
    const float* W2 = (const float*)d_in[4];
    const float* b2 = (const float*)d_in[5];
    const float* W3 = (const float*)d_in[6];
    const float* b3 = (const float*)d_in[7];
    const float* g1 = (const float*)d_in[8];
    const float* be1 = (const float*)d_in[9];
    const float* g2 = (const float*)d_in[10];
    const float* be2 = (const float*)d_in[11];
    const float* g3 = (const float*)d_in[12];
    const float* be3 = (const float*)d_in[13];
    float* out = (float*)d_out;

    const int N = N_NODES, E = N_EDGES;
    char* w = (char*)d_ws;
    unsigned short* hb   = (unsigned short*)w; w += (size_t)N * 128 * 2;
    unsigned short* midb = (unsigned short*)w; w += (size_t)N * 128 * 2;
    unsigned short* w1s  = (unsigned short*)w; w += (size_t)64 * 128 * 2;
    unsigned short* w2s  = (unsigned short*)w; w += (size_t)128 * 128 * 2;
    unsigned short* w3s  = (unsigned short*)w; w += (size_t)128 * 128 * 2;
    int*   col    = (int*)w;    w += (size_t)E * sizeof(int);
    int*   rowp   = (int*)w;    w += (size_t)(N + 1) * sizeof(int);
    int*   cursor = (int*)w;    w += (size_t)N * sizeof(int);
    int*   deg    = (int*)w;    w += (size_t)N * sizeof(int);
    float* invc   = (float*)w;  w += (size_t)N * sizeof(float);
    int*   parts  = (int*)w;    w += (size_t)SCAN_NBLK * sizeof(int);

    hipMemsetAsync(deg, 0, (size_t)N * sizeof(int), stream);

    // K1: gemm1 (f32 x, in-kernel W1 swizzle) | count | wswz — independent work
    mega1_kernel<<<GB1 + CB + WB, 256, 0, stream>>>(x, w1s, b1, hb, ei, deg,
                                                    W1, W2, W3, w1s, w2s, w3s, N, E);
    deg_partial_kernel<<<SCAN_NBLK, SCAN_BLOCK, 0, stream>>>(deg, parts, N);
    scan_final_kernel<<<SCAN_NBLK, SCAN_BLOCK, 0, stream>>>(deg, parts, rowp, cursor, invc, N);
    fill_kernel<<<(E + 255) / 256, 256, 0, stream>>>(ei, cursor, col, E);

    const int gemm_blocks = (N + 63) / 64;
    const int agg_blocks  = (N + 15) / 16;

    agg_norm_kernel<1><<<agg_blocks, 256, 0, stream>>>(hb, rowp, col, invc, g1, be1, midb, N);
    gemm_mfma_kernel<128><<<gemm_blocks, 256, 0, stream>>>(midb, w2s, b2, hb, N);
    agg_norm_kernel<1><<<agg_blocks, 256, 0, stream>>>(hb, rowp, col, invc, g2, be2, midb, N);
    gemm_mfma_kernel<128><<<gemm_blocks, 256, 0, stream>>>(midb, w3s, b3, hb, N);
    agg_norm_kernel<0><<<agg_blocks, 256, 0, stream>>>(hb, rowp, col, invc, g3, be3, out, N);
}

// Round 21
// 184.071 us; speedup vs baseline: 1.0686x; 1.0073x over previous
//
#include <hip/hip_runtime.h>
#include <hip/hip_bf16.h>

#define N_NODES 50000
#define N_EDGES 600000
#define HID 128
#define LN_EPS 1e-5f

#define SCAN_BLOCK 1024
#define SCAN_NBLK ((N_NODES + SCAN_BLOCK - 1) / SCAN_BLOCK)   // 49

#define GB1 ((N_NODES + 63) / 64)        // 782 gemm1 blocks
#define CB  ((N_EDGES + 255) / 256)      // 2344 count blocks
#define WB  (((64 + 256) * 128) / 256)   // 160 wswz blocks

typedef __attribute__((ext_vector_type(8))) short bf16x8;
typedef __attribute__((ext_vector_type(4))) float f32x4;

// f32 -> bf16 round-to-nearest-even
static __device__ __forceinline__ unsigned short f2bf(float f) {
    union { float f; unsigned u; } v; v.f = f;
    unsigned u = v.u;
    u += 0x7fffu + ((u >> 16) & 1u);
    return (unsigned short)(u >> 16);
}
static __device__ __forceinline__ float bflo(unsigned u) {
    union { unsigned u; float f; } c; c.u = u << 16; return c.f;
}
static __device__ __forceinline__ float bfhi(unsigned u) {
    union { unsigned u; float f; } c; c.u = u & 0xffff0000u; return c.f;
}

// ---------------------------------------------------------------- K1: gemm1 | count | wswz
// All three phases depend only on kernel-entry inputs -> safe blockIdx branch.
__global__ __launch_bounds__(256) void mega1_kernel(
    const float* __restrict__ x,
    const float* __restrict__ b1,
    unsigned short* __restrict__ hb,
    const int* __restrict__ ei,
    int* __restrict__ deg,
    const float* __restrict__ W1,
    const float* __restrict__ W2,
    const float* __restrict__ W3,
    unsigned short* __restrict__ d1,
    unsigned short* __restrict__ d2,
    unsigned short* __restrict__ d3, int N, int E) {
    __shared__ unsigned short Bl[64 * 128];
    __shared__ float bl[128];
    int bid = blockIdx.x;
    int t = threadIdx.x;

    if (bid < GB1) {
        // gemm1: hb = bf16(x @ W1 + b1), W1 swizzled in-kernel from f32
        for (int i = t; i < 64 * 128; i += 256) {
            int k = i >> 7, col = i & 127;
            Bl[(((k >> 3) * 128) + col) * 8 + (k & 7)] = f2bf(W1[i]);
        }
        if (t < 128) bl[t] = b1[t];
        __syncthreads();

        int lane = t & 63;
        int w = t >> 6;
        int r0 = bid * 64 + w * 16;
        int colb = lane & 15;
        int kg = lane >> 4;
        int rowa = min(r0 + colb, N - 1);

        f32x4 acc[8];
#pragma unroll
        for (int c = 0; c < 8; ++c) acc[c] = (f32x4){0.f, 0.f, 0.f, 0.f};

        const bf16x8* Blv = (const bf16x8*)Bl;
        for (int s = 0; s < 64; s += 32) {
            bf16x8 afrag;
            float4 a0 = *(const float4*)&x[(size_t)rowa * 64 + s + kg * 8];
            float4 a1 = *(const float4*)&x[(size_t)rowa * 64 + s + kg * 8 + 4];
            afrag[0] = (short)f2bf(a0.x); afrag[1] = (short)f2bf(a0.y);
            afrag[2] = (short)f2bf(a0.z); afrag[3] = (short)f2bf(a0.w);
            afrag[4] = (short)f2bf(a1.x); afrag[5] = (short)f2bf(a1.y);
            afrag[6] = (short)f2bf(a1.z); afrag[7] = (short)f2bf(a1.w);
            int kb = (s >> 3) + kg;
#pragma unroll
            for (int c = 0; c < 8; ++c) {
                bf16x8 bfrag = Blv[kb * 128 + c * 16 + colb];
                acc[c] = __builtin_amdgcn_mfma_f32_16x16x32_bf16(afrag, bfrag, acc[c], 0, 0, 0);
            }
        }
#pragma unroll
        for (int c = 0; c < 8; ++c) {
            int col = c * 16 + colb;
            float bv = bl[col];
#pragma unroll
            for (int r = 0; r < 4; ++r) {
                int ro = r0 + kg * 4 + r;
                if (ro < N) hb[(size_t)ro * 128 + col] = f2bf(acc[c][r] + bv);
            }
        }
    } else if (bid < GB1 + CB) {
        int i = (bid - GB1) * 256 + t;
        if (i < E) atomicAdd(&deg[ei[E + i]], 1);
    } else {
        int i = (bid - GB1 - CB) * 256 + t;
        const float* W; unsigned short* dst; int idx;
        if (i < 64 * 128)              { W = W1; dst = d1; idx = i; }
        else if (i < (64 + 128) * 128) { W = W2; dst = d2; idx = i - 64 * 128; }
        else if (i < (64 + 256) * 128) { W = W3; dst = d3; idx = i - (64 + 128) * 128; }
        else return;
        int k = idx >> 7, col = idx & 127;
        dst[(((k >> 3) * 128) + col) * 8 + (k & 7)] = f2bf(W[idx]);
    }
}

// ---------------------------------------------------------------- CSR scan
__global__ __launch_bounds__(SCAN_BLOCK) void deg_partial_kernel(const int* __restrict__ deg,
                                                                 int* __restrict__ partials, int n) {
    int t = threadIdx.x;
    int i = blockIdx.x * SCAN_BLOCK + t;
    int v = (i < n) ? deg[i] : 0;
    int s = v;
#pragma unroll
    for (int off = 1; off < 64; off <<= 1) s += __shfl_xor(s, off);
    __shared__ int ws[SCAN_BLOCK / 64];
    if ((t & 63) == 0) ws[t >> 6] = s;
    __syncthreads();
    if (t == 0) {
        int tot = 0;
#pragma unroll
        for (int w = 0; w < SCAN_BLOCK / 64; ++w) tot += ws[w];
        partials[blockIdx.x] = tot;
    }
}

// block-exclusive scan; each block serially prefixes the 49 partials itself.
__global__ __launch_bounds__(SCAN_BLOCK) void scan_final_kernel(const int* __restrict__ deg,
                                                                const int* __restrict__ partials,
                                                                int* __restrict__ row_ptr,
                                                                int* __restrict__ cursor,
                                                                float* __restrict__ inv_cnt, int n) {
    __shared__ int base_sh;
    __shared__ int ws[SCAN_BLOCK / 64];
    int t = threadIdx.x;
    if (t == 0) {
        int pre = 0, tot = 0;
        for (int i = 0; i < SCAN_NBLK; ++i) {
            int p = partials[i];
            if (i < (int)blockIdx.x) pre += p;
            tot += p;
        }
        base_sh = pre;
        if (blockIdx.x == 0) row_ptr[n] = tot;
    }
    int i = blockIdx.x * SCAN_BLOCK + t;
    int v = (i < n) ? deg[i] : 0;
    int lane = t & 63, wid = t >> 6;
    int incl = v;
#pragma unroll
    for (int off = 1; off < 64; off <<= 1) {
        int x = __shfl_up(incl, off);
        if (lane >= off) incl += x;
    }
    if (lane == 63) ws[wid] = incl;
    __syncthreads();
    int woff = 0;
    for (int w = 0; w < wid; ++w) woff += ws[w];
    int excl = base_sh + woff + (incl - v);
    if (i < n) {
        row_ptr[i] = excl;
        cursor[i]  = excl;
        inv_cnt[i] = 1.0f / (float)(v + 1);
    }
}

__global__ __launch_bounds__(256) void fill_kernel(const int* __restrict__ ei,
                                                   int* __restrict__ cursor,
                                                   int* __restrict__ col, int E) {
    int i = blockIdx.x * blockDim.x + threadIdx.x;
    if (i < E) {
        int s = ei[i];
        int d = ei[E + i];
        int p = atomicAdd(&cursor[d], 1);
        col[p] = s;
    }
}

// ---------------------------------------------------------------- MFMA GEMM (layers 2,3)
template <int K>
__global__ __launch_bounds__(256) void gemm_mfma_kernel(
    const unsigned short* __restrict__ Ab,
    const unsigned short* __restrict__ Wswz,
    const float* __restrict__ bias,
    unsigned short* __restrict__ out, int N) {
    __shared__ unsigned short Bl[K * 128];
    __shared__ float bl[128];
    int t = threadIdx.x;
    for (int i = t; i < K * 16; i += 256)
        ((int4*)Bl)[i] = ((const int4*)Wswz)[i];
    if (t < 128) bl[t] = bias[t];
    __syncthreads();

    int lane = t & 63;
    int w = t >> 6;
    int r0 = blockIdx.x * 64 + w * 16;
    int colb = lane & 15;
    int kg = lane >> 4;
    int rowa = min(r0 + colb, N - 1);

    f32x4 acc[8];
#pragma unroll
    for (int c = 0; c < 8; ++c) acc[c] = (f32x4){0.f, 0.f, 0.f, 0.f};

    const bf16x8* Blv = (const bf16x8*)Bl;
    for (int s = 0; s < K; s += 32) {
        bf16x8 afrag = *(const bf16x8*)&Ab[(size_t)rowa * K + s + kg * 8];
        int kb = (s >> 3) + kg;
#pragma unroll
        for (int c = 0; c < 8; ++c) {
            bf16x8 bfrag = Blv[kb * 128 + c * 16 + colb];
            acc[c] = __builtin_amdgcn_mfma_f32_16x16x32_bf16(afrag, bfrag, acc[c], 0, 0, 0);
        }
    }
#pragma unroll
    for (int c = 0; c < 8; ++c) {
        int col = c * 16 + colb;
        float bv = bl[col];
#pragma unroll
        for (int r = 0; r < 4; ++r) {
            int ro = r0 + kg * 4 + r;
            if (ro < N) out[(size_t)ro * 128 + col] = f2bf(acc[c][r] + bv);
        }
    }
}

// ------------------------------------------------- aggregate + mean + ReLU + LN
// 4 nodes per wave, 16 lanes per node, dwordx4/lane. 8-edge batches.
template <int BF16OUT>
__global__ __launch_bounds__(256) void agg_norm_kernel(
    const unsigned short* __restrict__ hb,
    const int* __restrict__ row_ptr,
    const int* __restrict__ col,
    const float* __restrict__ inv_cnt,
    const float* __restrict__ g, const float* __restrict__ be,
    void* __restrict__ outp, int N) {
    int tid  = blockIdx.x * 256 + threadIdx.x;
    int wave = tid >> 6;
    int lane = threadIdx.x & 63;
    int sub  = lane >> 4;
    int lc   = lane & 15;
    int n    = wave * 4 + sub;
    bool act = n < N;
    int nc   = act ? n : N - 1;

    const uint4* h4 = (const uint4*)hb;

    float a[8];
    {
        uint4 u = h4[(size_t)nc * 16 + lc];
        a[0] = bflo(u.x); a[1] = bfhi(u.x);
        a[2] = bflo(u.y); a[3] = bfhi(u.y);
        a[4] = bflo(u.z); a[5] = bfhi(u.z);
        a[6] = bflo(u.w); a[7] = bfhi(u.w);
    }

    int beg = row_ptr[nc], end = row_ptr[nc + 1];
    int cnt = end - beg;
    int lim = min(cnt, 32);
    int c0 = (lc < cnt)      ? col[beg + lc]      : nc;
    int c1 = (16 + lc < cnt) ? col[beg + 16 + lc] : nc;

    int wlim = lim;
    wlim = max(wlim, __shfl_xor(wlim, 16));
    wlim = max(wlim, __shfl_xor(wlim, 32));
    int nGrp = (wlim + 7) >> 3;

    for (int gi = 0; gi < nGrp; ++gi) {
        int e0 = gi * 8;
        int jj[8]; float mm[8];
#pragma unroll
        for (int q = 0; q < 8; ++q) {
            int iq = max(min(e0 + q, lim - 1), 0);
            mm[q] = (e0 + q < lim) ? 1.0f : 0.0f;
            int sl = sub * 16 + (iq & 15);
            int jA = __shfl(c0, sl);
            int jB = __shfl(c1, sl);
            jj[q] = (iq < 16) ? jA : jB;
        }
        uint4 u[8];
#pragma unroll
        for (int q = 0; q < 8; ++q) u[q] = h4[(size_t)jj[q] * 16 + lc];
#pragma unroll
        for (int q = 0; q < 8; ++q) {
            a[0] = fmaf(mm[q], bflo(u[q].x), a[0]); a[1] = fmaf(mm[q], bfhi(u[q].x), a[1]);
            a[2] = fmaf(mm[q], bflo(u[q].y), a[2]); a[3] = fmaf(mm[q], bfhi(u[q].y), a[3]);
            a[4] = fmaf(mm[q], bflo(u[q].z), a[4]); a[5] = fmaf(mm[q], bfhi(u[q].z), a[5]);
            a[6] = fmaf(mm[q], bflo(u[q].w), a[6]); a[7] = fmaf(mm[q], bfhi(u[q].w), a[7]);
        }
    }
    for (int e = 32; e < cnt; ++e) {
        int j = col[beg + e];
        uint4 u = h4[(size_t)j * 16 + lc];
        a[0] += bflo(u.x); a[1] += bfhi(u.x);
        a[2] += bflo(u.y); a[3] += bfhi(u.y);
        a[4] += bflo(u.z); a[5] += bfhi(u.z);
        a[6] += bflo(u.w); a[7] += bfhi(u.w);
    }

    float ic = inv_cnt[nc];
    float s[8], sum = 0.f, sq = 0.f;
#pragma unroll
    for (int k = 0; k < 8; ++k) {
        s[k] = fmaxf(a[k] * ic, 0.0f);
        sum += s[k];
        sq  += s[k] * s[k];
    }
#pragma unroll
    for (int off = 1; off < 16; off <<= 1) {
        sum += __shfl_xor(sum, off);
        sq  += __shfl_xor(sq, off);
    }
    float mu  = sum * (1.0f / 128.0f);
    float var = sq * (1.0f / 128.0f) - mu * mu;
    float rs  = rsqrtf(var + LN_EPS);

    const float4* gv  = (const float4*)g;
    const float4* bv  = (const float4*)be;
    float4 gA = gv[lc * 2], gB = gv[lc * 2 + 1];
    float4 bA = bv[lc * 2], bB = bv[lc * 2 + 1];
    float o[8];
    o[0] = gA.x * (s[0] - mu) * rs + bA.x;
    o[1] = gA.y * (s[1] - mu) * rs + bA.y;
    o[2] = gA.z * (s[2] - mu) * rs + bA.z;
    o[3] = gA.w * (s[3] - mu) * rs + bA.w;
    o[4] = gB.x * (s[4] - mu) * rs + bB.x;
    o[5] = gB.y * (s[5] - mu) * rs + bB.y;
    o[6] = gB.z * (s[6] - mu) * rs + bB.z;
    o[7] = gB.w * (s[7] - mu) * rs + bB.w;

    if (!act) return;
    if (BF16OUT) {
        uint4 p;
        p.x = (unsigned)f2bf(o[0]) | ((unsigned)f2bf(o[1]) << 16);
        p.y = (unsigned)f2bf(o[2]) | ((unsigned)f2bf(o[3]) << 16);
        p.z = (unsigned)f2bf(o[4]) | ((unsigned)f2bf(o[5]) << 16);
        p.w = (unsigned)f2bf(o[6]) | ((unsigned)f2bf(o[7]) << 16);
        ((uint4*)outp)[(size_t)nc * 16 + lc] = p;
    } else {
        float4 f0; f0.x = o[0]; f0.y = o[1]; f0.z = o[2]; f0.w = o[3];
        float4 f1; f1.x = o[4]; f1.y = o[5]; f1.z = o[6]; f1.w = o[7];
        ((float4*)outp)[(size_t)nc * 32 + lc * 2]     = f0;
        ((float4*)outp)[(size_t)nc * 32 + lc * 2 + 1] = f1;
    }
}

// ---------------------------------------------------------------- launch
extern "C" void kernel_launch(void* const* d_in, const int* in_sizes, int n_in,
                              void* d_out, int out_size, void* d_ws, size_t ws_size,
                              hipStream_t stream) {
    const float* x  = (const float*)d_in[0];
    const int*   ei = (const int*)d_in[1];
    const float* W1 = (const float*)d_in[2];
    const float* b1 = (const float*)d_in[3];
    const float* W2 = (const float*)d_in[4];
    const float* b2 = (const float*)d_in[5];
    const float* W3 = (const float*)d_in[6];
    const float* b3 = (const float*)d_in[7];
    const float* g1 = (const float*)d_in[8];
    const float* be1 = (const float*)d_in[9];
    const float* g2 = (const float*)d_in[10];
    const float* be2 = (const float*)d_in[11];
    const float* g3 = (const float*)d_in[12];
    const float* be3 = (const float*)d_in[13];
    float* out = (float*)d_out;

    const int N = N_NODES, E = N_EDGES;
    char* w = (char*)d_ws;
    unsigned short* hb   = (unsigned short*)w; w += (size_t)N * 128 * 2;
    unsigned short* midb = (unsigned short*)w; w += (size_t)N * 128 * 2;
    unsigned short* w1s  = (unsigned short*)w; w += (size_t)64 * 128 * 2;
    unsigned short* w2s  = (unsigned short*)w; w += (size_t)128 * 128 * 2;
    unsigned short* w3s  = (unsigned short*)w; w += (size_t)128 * 128 * 2;
    int*   col    = (int*)w;    w += (size_t)E * sizeof(int);
    int*   rowp   = (int*)w;    w += (size_t)(N + 1) * sizeof(int);
    int*   cursor = (int*)w;    w += (size_t)N * sizeof(int);
    int*   deg    = (int*)w;    w += (size_t)N * sizeof(int);
    float* invc   = (float*)w;  w += (size_t)N * sizeof(float);
    int*   parts  = (int*)w;    w += (size_t)SCAN_NBLK * sizeof(int);

    hipMemsetAsync(deg, 0, (size_t)N * sizeof(int), stream);

    // K1: gemm1 (f32 x, in-kernel W1 swizzle) | count | wswz — independent work
    mega1_kernel<<<GB1 + CB + WB, 256, 0, stream>>>(x, b1, hb, ei, deg,
                                                    W1, W2, W3, w1s, w2s, w3s, N, E);
    deg_partial_kernel<<<SCAN_NBLK, SCAN_BLOCK, 0, stream>>>(deg, parts, N);
    scan_final_kernel<<<SCAN_NBLK, SCAN_BLOCK, 0, stream>>>(deg, parts, rowp, cursor, invc, N);
    fill_kernel<<<(E + 255) / 256, 256, 0, stream>>>(ei, cursor, col, E);

    const int gemm_blocks = (N + 63) / 64;
    const int agg_blocks  = (N + 15) / 16;

    agg_norm_kernel<1><<<agg_blocks, 256, 0, stream>>>(hb, rowp, col, invc, g1, be1, midb, N);
    gemm_mfma_kernel<128><<<gemm_blocks, 256, 0, stream>>>(midb, w2s, b2, hb, N);
    agg_norm_kernel<1><<<agg_blocks, 256, 0, stream>>>(hb, rowp, col, invc, g2, be2, midb, N);
    gemm_mfma_kernel<128><<<gemm_blocks, 256, 0, stream>>>(midb, w3s, b3, hb, N);
    agg_norm_kernel<0><<<agg_blocks, 256, 0, stream>>>(hb, rowp, col, invc, g3, be3, out, N);
}